// Round 4
// baseline (158.605 us; speedup 1.0000x reference)
//
#include <hip/hip_runtime.h>

#define BB 8
#define NN 6
#define DD 45
#define CC 64
#define FHH 8
#define FWW 22
#define GXX 64
#define GYY 64
#define GZZ 32
#define NPOINTS (BB*NN*DD*FHH*FWW)       // 380160
#define NSITES (BB*NN*FHH*FWW)           // 8448
#define NFEATT (NSITES*CC)               // 540672
#define NSLABS (BB*GZZ*GXX)              // 16384 (b,nz,nx) slabs
#define CAP 1024                         // worst-case slab load ~600

// ws layout (bytes): count[NSLABS] | bucket[NSLABS*CAP] | featT[NFEATT]
#define WS_COUNT_OFF 0
#define WS_BUCKET_OFF ((size_t)NSLABS * 4)
#define WS_FEATT_OFF (WS_BUCKET_OFF + (size_t)NSLABS * CAP * 4)
#define WS_NEEDED (WS_FEATT_OFF + (size_t)NFEATT * 4)

__global__ __launch_bounds__(256) void lss_zero(float4* __restrict__ p, int n4) {
    int i = blockIdx.x * blockDim.x + threadIdx.x;
    int stride = gridDim.x * blockDim.x;
    float4 z = make_float4(0.f, 0.f, 0.f, 0.f);
    for (; i < n4; i += stride) p[i] = z;
}

// feature [B,N,C,FH,FW] -> featT [B,N,FH,FW,C]; also zeroes count[].
__global__ __launch_bounds__(256) void lss_featT(const float* __restrict__ feature,
                                                 float* __restrict__ featT,
                                                 int* __restrict__ count) {
    int idx = blockIdx.x * 256 + threadIdx.x;        // < NFEATT (540672 = 2112*256)
    if (idx < NSLABS) count[idx] = 0;
    int c = idx & 63;
    int site = idx >> 6;                             // (cam*FH + h)*FW + w
    int hw = site % (FHH * FWW);
    int cam = site / (FHH * FWW);
    featT[idx] = feature[(cam * CC + c) * (FHH * FWW) + hw];
}

// Per-point geometry -> (slab, ny); append to slab bucket.
__global__ __launch_bounds__(256) void lss_build(
    const float* __restrict__ rots, const float* __restrict__ trans,
    const float* __restrict__ intr,
    int* __restrict__ count, int* __restrict__ bucket)
{
    int p = blockIdx.x * 256 + threadIdx.x;          // < NPOINTS
    int w = p % FWW;
    int t = p / FWW;
    int h = t % FHH; t /= FHH;
    int di = t % DD; t /= DD;
    int n = t % NN;
    int b = t / NN;

    float d = (float)(di + 1);
    float x = (float)(351.0 * (double)w / 21.0);
    float y = (float)(127.0 * (double)h / 7.0);

    const float* K = intr + (b * NN + n) * 9;
    double k00 = K[0], k01 = K[1], k02 = K[2];
    double k10 = K[3], k11 = K[4], k12 = K[5];
    double k20 = K[6], k21 = K[7], k22 = K[8];
    double det = k00 * (k11 * k22 - k12 * k21)
               - k01 * (k10 * k22 - k12 * k20)
               + k02 * (k10 * k21 - k11 * k20);
    double id = 1.0 / det;
    float i00 = (float)(( k11 * k22 - k12 * k21) * id);
    float i01 = (float)((-k01 * k22 + k02 * k21) * id);
    float i02 = (float)(( k01 * k12 - k02 * k11) * id);
    float i10 = (float)((-k10 * k22 + k12 * k20) * id);
    float i11 = (float)(( k00 * k22 - k02 * k20) * id);
    float i12 = (float)((-k00 * k12 + k02 * k10) * id);
    float i20 = (float)(( k10 * k21 - k11 * k20) * id);
    float i21 = (float)((-k00 * k21 + k01 * k20) * id);
    float i22 = (float)(( k00 * k11 - k01 * k10) * id);

    float p0 = x * d, p1 = y * d, p2 = d;
    float c0 = i00 * p0 + i01 * p1 + i02 * p2;
    float c1 = i10 * p0 + i11 * p1 + i12 * p2;
    float c2 = i20 * p0 + i21 * p1 + i22 * p2;

    const float* R = rots + (b * NN + n) * 9;
    const float* T = trans + (b * NN + n) * 3;
    float g0 = R[0] * c0 + R[1] * c1 + R[2] * c2 + T[0];
    float g1 = R[3] * c0 + R[4] * c1 + R[5] * c2 + T[1];
    float g2 = R[6] * c0 + R[7] * c1 + R[8] * c2 + T[2];

    int nx = (int)((g0 + 16.0f) / 0.5f);
    int ny = (int)((g2 + 16.0f) / 0.5f);
    int nz = (int)((g1 + 8.0f)  / 0.5f);
    if (!((nx >= 0) & (nx < GXX) & (ny >= 0) & (ny < GYY) & (nz >= 0) & (nz < GZZ)))
        return;

    int slab = (b * GZZ + nz) * GXX + nx;
    int rank = atomicAdd(&count[slab], 1);
    if (rank < CAP) bucket[slab * CAP + rank] = (p << 6) | ny;
}

// One block per slab (b,nz,nx): 64 ny-voxels x 64 channels.
// 4 waves share the slab's entries; LDS ds_add accumulate; coalesced dense write.
__global__ __launch_bounds__(256) void lss_out2(
    const float* __restrict__ depth, const float* __restrict__ featT,
    const int* __restrict__ count, const int* __restrict__ bucket,
    float* __restrict__ out)
{
    int slab = blockIdx.x;                 // (b*GZ + nz)*GX + nx
    int nx = slab % GXX;
    int t2 = slab / GXX;
    int nz = t2 % GZZ;
    int b  = t2 / GZZ;
    int tid = threadIdx.x;

    int cnt = count[slab];
    if (cnt > CAP) cnt = CAP;

    // output base for this slab's (c, ny) tile
    size_t obase = (((size_t)b * CC * GZZ + nz) * GXX + nx) * GYY;  // + c*(GZZ*GXX*GYY) + ny

    if (cnt == 0) {
        // fast path: stream 16 KB of zeros
        float4 z = make_float4(0.f, 0.f, 0.f, 0.f);
        #pragma unroll
        for (int k = 0; k < 4; ++k) {
            int i = tid + k * 256;
            int c   = i >> 4;
            int ny4 = i & 15;
            size_t o = obase + (size_t)c * (GZZ * GXX * GYY) + ny4 * 4;
            *(float4*)(out + o) = z;
        }
        return;
    }

    __shared__ float tile[64][65];
    float* tf = &tile[0][0];
    for (int j = tid; j < 64 * 65; j += 256) tf[j] = 0.f;
    __syncthreads();

    int wid = tid >> 6;
    int lane = tid & 63;
    int base = slab * CAP;
    for (int e = wid; e < cnt; e += 4) {
        int entry = bucket[base + e];            // wave-uniform (broadcast)
        int p  = entry >> 6;
        int ny = entry & 63;
        float dval = depth[p];                   // depth layout == point order
        int rem = p / FWW;  int w = p - rem * FWW;
        int rem2 = rem / FHH; int h = rem - rem2 * FHH;
        int cam = rem2 / DD;
        int site = (cam * FHH + h) * FWW + w;
        float v = dval * featT[site * 64 + lane];  // 256B contiguous per wave
        atomicAdd(&tile[ny][lane], v);             // ds_add_f32, fire-and-forget
    }
    __syncthreads();

    #pragma unroll
    for (int k = 0; k < 4; ++k) {
        int i = tid + k * 256;
        int c   = i >> 4;
        int ny4 = i & 15;
        float4 v;
        v.x = tile[ny4 * 4 + 0][c];
        v.y = tile[ny4 * 4 + 1][c];
        v.z = tile[ny4 * 4 + 2][c];
        v.w = tile[ny4 * 4 + 3][c];
        size_t o = obase + (size_t)c * (GZZ * GXX * GYY) + ny4 * 4;
        *(float4*)(out + o) = v;
    }
}

// ---- fallback (R1 path) ----
__global__ __launch_bounds__(256) void lss_scatter_direct(
    const float* __restrict__ depth, const float* __restrict__ feature,
    const float* __restrict__ rots, const float* __restrict__ trans,
    const float* __restrict__ intr, float* __restrict__ out)
{
    int p = blockIdx.x * 4 + (threadIdx.x >> 6);
    int lane = threadIdx.x & 63;
    int w = p % FWW;
    int t = p / FWW;
    int h = t % FHH; t /= FHH;
    int di = t % DD; t /= DD;
    int n = t % NN;
    int b = t / NN;
    float d = (float)(di + 1);
    float x = (float)(351.0 * (double)w / 21.0);
    float y = (float)(127.0 * (double)h / 7.0);
    const float* K = intr + (b * NN + n) * 9;
    double k00 = K[0], k01 = K[1], k02 = K[2];
    double k10 = K[3], k11 = K[4], k12 = K[5];
    double k20 = K[6], k21 = K[7], k22 = K[8];
    double det = k00*(k11*k22-k12*k21) - k01*(k10*k22-k12*k20) + k02*(k10*k21-k11*k20);
    double id = 1.0 / det;
    float i00=(float)((k11*k22-k12*k21)*id), i01=(float)((-k01*k22+k02*k21)*id), i02=(float)((k01*k12-k02*k11)*id);
    float i10=(float)((-k10*k22+k12*k20)*id), i11=(float)((k00*k22-k02*k20)*id), i12=(float)((-k00*k12+k02*k10)*id);
    float i20=(float)((k10*k21-k11*k20)*id), i21=(float)((-k00*k21+k01*k20)*id), i22=(float)((k00*k11-k01*k10)*id);
    float p0 = x * d, p1 = y * d, p2 = d;
    float c0 = i00*p0 + i01*p1 + i02*p2;
    float c1 = i10*p0 + i11*p1 + i12*p2;
    float c2 = i20*p0 + i21*p1 + i22*p2;
    const float* R = rots + (b * NN + n) * 9;
    const float* T = trans + (b * NN + n) * 3;
    float g0 = R[0]*c0 + R[1]*c1 + R[2]*c2 + T[0];
    float g1 = R[3]*c0 + R[4]*c1 + R[5]*c2 + T[1];
    float g2 = R[6]*c0 + R[7]*c1 + R[8]*c2 + T[2];
    int nx = (int)((g0 + 16.0f) / 0.5f);
    int ny = (int)((g2 + 16.0f) / 0.5f);
    int nz = (int)((g1 + 8.0f)  / 0.5f);
    if (!((nx >= 0) & (nx < GXX) & (ny >= 0) & (ny < GYY) & (nz >= 0) & (nz < GZZ)))
        return;
    float dv = depth[(((b * NN + n) * DD + di) * FHH + h) * FWW + w];
    float fv = feature[(((b * NN + n) * CC + lane) * FHH + h) * FWW + w];
    size_t oidx = ((((size_t)b * CC + lane) * GZZ + nz) * GXX + nx) * GYY + ny;
    atomicAdd(out + oidx, dv * fv);
}

extern "C" void kernel_launch(void* const* d_in, const int* in_sizes, int n_in,
                              void* d_out, int out_size, void* d_ws, size_t ws_size,
                              hipStream_t stream) {
    const float* depth   = (const float*)d_in[0];
    const float* feature = (const float*)d_in[1];
    const float* rots    = (const float*)d_in[2];
    const float* trans   = (const float*)d_in[3];
    const float* intr    = (const float*)d_in[4];
    float* out = (float*)d_out;

    if (ws_size >= WS_NEEDED) {
        int*   count  = (int*)((char*)d_ws + WS_COUNT_OFF);
        int*   bucket = (int*)((char*)d_ws + WS_BUCKET_OFF);
        float* featT  = (float*)((char*)d_ws + WS_FEATT_OFF);

        // 1) featT transpose + zero counts
        lss_featT<<<NFEATT / 256, 256, 0, stream>>>(feature, featT, count);
        // 2) build per-slab buckets (NPOINTS = 1485*256)
        lss_build<<<NPOINTS / 256, 256, 0, stream>>>(rots, trans, intr, count, bucket);
        // 3) dense output generation (writes every element; no out-zero needed)
        lss_out2<<<NSLABS, 256, 0, stream>>>(depth, featT, count, bucket, out);
    } else {
        lss_zero<<<4096, 256, 0, stream>>>((float4*)out, out_size / 4);
        lss_scatter_direct<<<NPOINTS / 4, 256, 0, stream>>>(depth, feature, rots, trans, intr, out);
    }
}

// Round 5
// 124.535 us; speedup vs baseline: 1.2736x; 1.2736x over previous
//
#include <hip/hip_runtime.h>

#define BB 8
#define NN 6
#define DD 45
#define CC 64
#define FHH 8
#define FWW 22
#define GXX 64
#define GYY 64
#define GZZ 32
#define NPOINTS (BB*NN*DD*FHH*FWW)       // 380160 = 1485*256
#define NSITES (BB*NN*FHH*FWW)           // 8448
#define NFEATT (NSITES*CC)               // 540672 = 2112*256
#define ROWS (BB*GZZ)                    // 256 (b,nz) rows
#define CAPR 8192                        // worst row ~3500 entries -> 2.3x margin

// ws layout (bytes): cnt[ROWS] | bucket2[ROWS*CAPR] (int2) | featT[NFEATT]
#define WS_CNT_OFF 0
#define WS_BUCKET_OFF 1024
#define WS_FEATT_OFF (WS_BUCKET_OFF + (size_t)ROWS * CAPR * 8)
#define WS_NEEDED (WS_FEATT_OFF + (size_t)NFEATT * 4)

__global__ __launch_bounds__(256) void lss_zero(float4* __restrict__ p, int n4) {
    int i = blockIdx.x * blockDim.x + threadIdx.x;
    int stride = gridDim.x * blockDim.x;
    float4 z = make_float4(0.f, 0.f, 0.f, 0.f);
    for (; i < n4; i += stride) p[i] = z;
}

// feature [B,N,C,FH,FW] -> featT [B,N,FH,FW,C]; also zeroes cnt[].
__global__ __launch_bounds__(256) void lss_featT(const float* __restrict__ feature,
                                                 float* __restrict__ featT,
                                                 int* __restrict__ cnt) {
    int idx = blockIdx.x * 256 + threadIdx.x;        // < NFEATT
    if (idx < ROWS) cnt[idx] = 0;
    int c = idx & 63;
    int site = idx >> 6;                             // (cam*FH + h)*FW + w
    int hw = site % (FHH * FWW);
    int cam = site / (FHH * FWW);
    featT[idx] = feature[(cam * CC + c) * (FHH * FWW) + hw];
}

// Per-point geometry -> (row=(b,nz), site, nx, ny); append to row bucket.
// Wave-aggregated rank atomics (rows are heavily shared within a wave).
__global__ __launch_bounds__(256) void lss_build(
    const float* __restrict__ rots, const float* __restrict__ trans,
    const float* __restrict__ intr,
    int* __restrict__ cnt, int2* __restrict__ bucket2)
{
    int p = blockIdx.x * 256 + threadIdx.x;          // < NPOINTS
    int lane = threadIdx.x & 63;
    int w = p % FWW;
    int t = p / FWW;
    int h = t % FHH; t /= FHH;
    int di = t % DD; t /= DD;
    int n = t % NN;
    int b = t / NN;

    float d = (float)(di + 1);
    float x = (float)(351.0 * (double)w / 21.0);
    float y = (float)(127.0 * (double)h / 7.0);

    const float* K = intr + (b * NN + n) * 9;
    double k00 = K[0], k01 = K[1], k02 = K[2];
    double k10 = K[3], k11 = K[4], k12 = K[5];
    double k20 = K[6], k21 = K[7], k22 = K[8];
    double det = k00 * (k11 * k22 - k12 * k21)
               - k01 * (k10 * k22 - k12 * k20)
               + k02 * (k10 * k21 - k11 * k20);
    double id = 1.0 / det;
    float i00 = (float)(( k11 * k22 - k12 * k21) * id);
    float i01 = (float)((-k01 * k22 + k02 * k21) * id);
    float i02 = (float)(( k01 * k12 - k02 * k11) * id);
    float i10 = (float)((-k10 * k22 + k12 * k20) * id);
    float i11 = (float)(( k00 * k22 - k02 * k20) * id);
    float i12 = (float)((-k00 * k12 + k02 * k10) * id);
    float i20 = (float)(( k10 * k21 - k11 * k20) * id);
    float i21 = (float)((-k00 * k21 + k01 * k20) * id);
    float i22 = (float)(( k00 * k11 - k01 * k10) * id);

    float p0 = x * d, p1 = y * d, p2 = d;
    float c0 = i00 * p0 + i01 * p1 + i02 * p2;
    float c1 = i10 * p0 + i11 * p1 + i12 * p2;
    float c2 = i20 * p0 + i21 * p1 + i22 * p2;

    const float* R = rots + (b * NN + n) * 9;
    const float* T = trans + (b * NN + n) * 3;
    float g0 = R[0] * c0 + R[1] * c1 + R[2] * c2 + T[0];
    float g1 = R[3] * c0 + R[4] * c1 + R[5] * c2 + T[1];
    float g2 = R[6] * c0 + R[7] * c1 + R[8] * c2 + T[2];

    int nx = (int)((g0 + 16.0f) / 0.5f);
    int ny = (int)((g2 + 16.0f) / 0.5f);
    int nz = (int)((g1 + 8.0f)  / 0.5f);
    bool valid = (nx >= 0) & (nx < GXX) & (ny >= 0) & (ny < GYY) & (nz >= 0) & (nz < GZZ);

    int row = valid ? (b * GZZ + nz) : -1;
    int site = (((b * NN + n) * FHH) + h) * FWW + w;
    int meta = (site << 12) | (nx << 6) | ny;        // site<8448 (14b) | nx(6b) | ny(6b)

    unsigned long long active = __ballot(valid);
    while (active) {
        int leader = __ffsll((unsigned long long)active) - 1;
        int lrow = __shfl(row, leader);
        unsigned long long same = __ballot(valid && (row == lrow));
        int base = 0;
        if (lane == leader) base = atomicAdd(&cnt[lrow], (int)__popcll(same));
        base = __shfl(base, leader);
        if (valid && (row == lrow)) {
            int off = (int)__popcll(same & ((1ull << lane) - 1ull));
            int rank = base + off;
            if (rank < CAPR) bucket2[lrow * CAPR + rank] = make_int2(p, meta);
        }
        active &= ~same;
    }
}

// One block per (row=(b,nz), c-chunk of 4): accumulate the row's entries into a
// [nx][ny][4] LDS tile, then write 4 CONTIGUOUS 16KB output planes [b,c,nz,:,:].
__global__ __launch_bounds__(256) void lss_out3(
    const float* __restrict__ depth, const float* __restrict__ featT,
    const int* __restrict__ cnt, const int2* __restrict__ bucket2,
    float* __restrict__ out)
{
    int bid = blockIdx.x;
    int ccb = bid & 15;                    // which 4-channel chunk
    int row = bid >> 4;                    // b*GZ + nz
    int b = row >> 5;
    int nz = row & 31;
    int tid = threadIdx.x;

    int scnt = cnt[row];
    if (scnt > CAPR) scnt = CAPR;

    if (scnt == 0) {
        float4 z = make_float4(0.f, 0.f, 0.f, 0.f);
        #pragma unroll
        for (int cc = 0; cc < 4; ++cc) {
            size_t ob = (((size_t)b * CC + (ccb * 4 + cc)) * GZZ + nz) * (GXX * GYY);
            for (int i = tid; i < 1024; i += 256)
                *(float4*)(out + ob + i * 4) = z;
        }
        return;
    }

    __shared__ float acc[GXX * GYY * 4];   // [nx][ny][cc], 64 KB
    {
        float4 z = make_float4(0.f, 0.f, 0.f, 0.f);
        float4* a4 = (float4*)acc;
        for (int i = tid; i < GXX * GYY; i += 256) a4[i] = z;
    }
    __syncthreads();

    const float4* fT = (const float4*)featT;   // fT[site*16 + ccb]
    const int2* bk = bucket2 + (size_t)row * CAPR;
    for (int e = tid; e < scnt; e += 256) {
        int2 en = bk[e];
        int p = en.x, meta = en.y;
        int site = meta >> 12;
        int nxny = meta & 4095;            // (nx<<6)|ny
        float dv = depth[p];
        float4 f = fT[site * 16 + ccb];
        int base = nxny * 4;
        atomicAdd(&acc[base + 0], dv * f.x);
        atomicAdd(&acc[base + 1], dv * f.y);
        atomicAdd(&acc[base + 2], dv * f.z);
        atomicAdd(&acc[base + 3], dv * f.w);
    }
    __syncthreads();

    #pragma unroll
    for (int cc = 0; cc < 4; ++cc) {
        size_t ob = (((size_t)b * CC + (ccb * 4 + cc)) * GZZ + nz) * (GXX * GYY);
        for (int i = tid; i < 1024; i += 256) {
            int o = i * 4;
            float4 v = make_float4(acc[(o + 0) * 4 + cc], acc[(o + 1) * 4 + cc],
                                   acc[(o + 2) * 4 + cc], acc[(o + 3) * 4 + cc]);
            *(float4*)(out + ob + o) = v;
        }
    }
}

// ---- fallback (R1 path) ----
__global__ __launch_bounds__(256) void lss_scatter_direct(
    const float* __restrict__ depth, const float* __restrict__ feature,
    const float* __restrict__ rots, const float* __restrict__ trans,
    const float* __restrict__ intr, float* __restrict__ out)
{
    int p = blockIdx.x * 4 + (threadIdx.x >> 6);
    int lane = threadIdx.x & 63;
    int w = p % FWW;
    int t = p / FWW;
    int h = t % FHH; t /= FHH;
    int di = t % DD; t /= DD;
    int n = t % NN;
    int b = t / NN;
    float d = (float)(di + 1);
    float x = (float)(351.0 * (double)w / 21.0);
    float y = (float)(127.0 * (double)h / 7.0);
    const float* K = intr + (b * NN + n) * 9;
    double k00 = K[0], k01 = K[1], k02 = K[2];
    double k10 = K[3], k11 = K[4], k12 = K[5];
    double k20 = K[6], k21 = K[7], k22 = K[8];
    double det = k00*(k11*k22-k12*k21) - k01*(k10*k22-k12*k20) + k02*(k10*k21-k11*k20);
    double id = 1.0 / det;
    float i00=(float)((k11*k22-k12*k21)*id), i01=(float)((-k01*k22+k02*k21)*id), i02=(float)((k01*k12-k02*k11)*id);
    float i10=(float)((-k10*k22+k12*k20)*id), i11=(float)((k00*k22-k02*k20)*id), i12=(float)((-k00*k12+k02*k10)*id);
    float i20=(float)((k10*k21-k11*k20)*id), i21=(float)((-k00*k21+k01*k20)*id), i22=(float)((k00*k11-k01*k10)*id);
    float p0 = x * d, p1 = y * d, p2 = d;
    float c0 = i00*p0 + i01*p1 + i02*p2;
    float c1 = i10*p0 + i11*p1 + i12*p2;
    float c2 = i20*p0 + i21*p1 + i22*p2;
    const float* R = rots + (b * NN + n) * 9;
    const float* T = trans + (b * NN + n) * 3;
    float g0 = R[0]*c0 + R[1]*c1 + R[2]*c2 + T[0];
    float g1 = R[3]*c0 + R[4]*c1 + R[5]*c2 + T[1];
    float g2 = R[6]*c0 + R[7]*c1 + R[8]*c2 + T[2];
    int nx = (int)((g0 + 16.0f) / 0.5f);
    int ny = (int)((g2 + 16.0f) / 0.5f);
    int nz = (int)((g1 + 8.0f)  / 0.5f);
    if (!((nx >= 0) & (nx < GXX) & (ny >= 0) & (ny < GYY) & (nz >= 0) & (nz < GZZ)))
        return;
    float dv = depth[(((b * NN + n) * DD + di) * FHH + h) * FWW + w];
    float fv = feature[(((b * NN + n) * CC + lane) * FHH + h) * FWW + w];
    size_t oidx = ((((size_t)b * CC + lane) * GZZ + nz) * GXX + nx) * GYY + ny;
    atomicAdd(out + oidx, dv * fv);
}

extern "C" void kernel_launch(void* const* d_in, const int* in_sizes, int n_in,
                              void* d_out, int out_size, void* d_ws, size_t ws_size,
                              hipStream_t stream) {
    const float* depth   = (const float*)d_in[0];
    const float* feature = (const float*)d_in[1];
    const float* rots    = (const float*)d_in[2];
    const float* trans   = (const float*)d_in[3];
    const float* intr    = (const float*)d_in[4];
    float* out = (float*)d_out;

    if (ws_size >= WS_NEEDED) {
        int*   cnt     = (int*)((char*)d_ws + WS_CNT_OFF);
        int2*  bucket2 = (int2*)((char*)d_ws + WS_BUCKET_OFF);
        float* featT   = (float*)((char*)d_ws + WS_FEATT_OFF);

        // 1) featT transpose + zero row counts
        lss_featT<<<NFEATT / 256, 256, 0, stream>>>(feature, featT, cnt);
        // 2) build per-(b,nz)-row buckets with wave-aggregated atomics
        lss_build<<<NPOINTS / 256, 256, 0, stream>>>(rots, trans, intr, cnt, bucket2);
        // 3) dense output: contiguous 16KB-plane writes per (b,c,nz)
        lss_out3<<<ROWS * 16, 256, 0, stream>>>(depth, featT, cnt, bucket2, out);
    } else {
        lss_zero<<<4096, 256, 0, stream>>>((float4*)out, out_size / 4);
        lss_scatter_direct<<<NPOINTS / 4, 256, 0, stream>>>(depth, feature, rots, trans, intr, out);
    }
}

// Round 6
// 97.375 us; speedup vs baseline: 1.6288x; 1.2789x over previous
//
#include <hip/hip_runtime.h>

#define BB 8
#define NN 6
#define DD 45
#define CC 64
#define FHH 8
#define FWW 22
#define GXX 64
#define GYY 64
#define GZZ 32
#define NPOINTS (BB*NN*DD*FHH*FWW)       // 380160 = 1485*256
#define NSITES (BB*NN*FHH*FWW)           // 8448
#define NFEATT (NSITES*CC)               // 540672 = 2112*256
#define ROWS (BB*GZZ)                    // 256 (b,nz) rows
#define CAPR 8192                        // worst row ~3500 entries -> 2.3x margin

// ws layout (bytes): cnt[ROWS] | bucket2[ROWS*CAPR] (int2) | featT[NFEATT]
#define WS_CNT_OFF 0
#define WS_BUCKET_OFF 1024
#define WS_FEATT_OFF (WS_BUCKET_OFF + (size_t)ROWS * CAPR * 8)
#define WS_NEEDED (WS_FEATT_OFF + (size_t)NFEATT * 4)

__global__ __launch_bounds__(256) void lss_zero(float4* __restrict__ p, int n4) {
    int i = blockIdx.x * blockDim.x + threadIdx.x;
    int stride = gridDim.x * blockDim.x;
    float4 z = make_float4(0.f, 0.f, 0.f, 0.f);
    for (; i < n4; i += stride) p[i] = z;
}

// feature [B,N,C,FH,FW] -> featT [B,N,FH,FW,C]; also zeroes cnt[].
__global__ __launch_bounds__(256) void lss_featT(const float* __restrict__ feature,
                                                 float* __restrict__ featT,
                                                 int* __restrict__ cnt) {
    int idx = blockIdx.x * 256 + threadIdx.x;        // < NFEATT
    if (idx < ROWS) cnt[idx] = 0;
    int c = idx & 63;
    int site = idx >> 6;                             // (cam*FH + h)*FW + w
    int hw = site % (FHH * FWW);
    int cam = site / (FHH * FWW);
    featT[idx] = feature[(cam * CC + c) * (FHH * FWW) + hw];
}

// Per-point geometry -> (row=(b,nz), dv, site, nx, ny); append to row bucket.
// Wave-aggregated rank atomics; depth is premultiplied into the entry.
__global__ __launch_bounds__(256) void lss_build(
    const float* __restrict__ depth,
    const float* __restrict__ rots, const float* __restrict__ trans,
    const float* __restrict__ intr,
    int* __restrict__ cnt, int2* __restrict__ bucket2)
{
    int p = blockIdx.x * 256 + threadIdx.x;          // < NPOINTS
    int lane = threadIdx.x & 63;
    int w = p % FWW;
    int t = p / FWW;
    int h = t % FHH; t /= FHH;
    int di = t % DD; t /= DD;
    int n = t % NN;
    int b = t / NN;

    float d = (float)(di + 1);
    float x = (float)(351.0 * (double)w / 21.0);
    float y = (float)(127.0 * (double)h / 7.0);

    const float* K = intr + (b * NN + n) * 9;
    double k00 = K[0], k01 = K[1], k02 = K[2];
    double k10 = K[3], k11 = K[4], k12 = K[5];
    double k20 = K[6], k21 = K[7], k22 = K[8];
    double det = k00 * (k11 * k22 - k12 * k21)
               - k01 * (k10 * k22 - k12 * k20)
               + k02 * (k10 * k21 - k11 * k20);
    double id = 1.0 / det;
    float i00 = (float)(( k11 * k22 - k12 * k21) * id);
    float i01 = (float)((-k01 * k22 + k02 * k21) * id);
    float i02 = (float)(( k01 * k12 - k02 * k11) * id);
    float i10 = (float)((-k10 * k22 + k12 * k20) * id);
    float i11 = (float)(( k00 * k22 - k02 * k20) * id);
    float i12 = (float)((-k00 * k12 + k02 * k10) * id);
    float i20 = (float)(( k10 * k21 - k11 * k20) * id);
    float i21 = (float)((-k00 * k21 + k01 * k20) * id);
    float i22 = (float)(( k00 * k11 - k01 * k10) * id);

    float p0 = x * d, p1 = y * d, p2 = d;
    float c0 = i00 * p0 + i01 * p1 + i02 * p2;
    float c1 = i10 * p0 + i11 * p1 + i12 * p2;
    float c2 = i20 * p0 + i21 * p1 + i22 * p2;

    const float* R = rots + (b * NN + n) * 9;
    const float* T = trans + (b * NN + n) * 3;
    float g0 = R[0] * c0 + R[1] * c1 + R[2] * c2 + T[0];
    float g1 = R[3] * c0 + R[4] * c1 + R[5] * c2 + T[1];
    float g2 = R[6] * c0 + R[7] * c1 + R[8] * c2 + T[2];

    int nx = (int)((g0 + 16.0f) / 0.5f);
    int ny = (int)((g2 + 16.0f) / 0.5f);
    int nz = (int)((g1 + 8.0f)  / 0.5f);
    bool valid = (nx >= 0) & (nx < GXX) & (ny >= 0) & (ny < GYY) & (nz >= 0) & (nz < GZZ);

    int row = valid ? (b * GZZ + nz) : -1;
    int site = (((b * NN + n) * FHH) + h) * FWW + w;
    int meta = (site << 12) | (nx << 6) | ny;        // site<8448 (14b) | nx(6b) | ny(6b)
    float dv = depth[p];                              // coalesced (depth layout == p order)

    unsigned long long active = __ballot(valid);
    while (active) {
        int leader = __ffsll((unsigned long long)active) - 1;
        int lrow = __shfl(row, leader);
        unsigned long long same = __ballot(valid && (row == lrow));
        int base = 0;
        if (lane == leader) base = atomicAdd(&cnt[lrow], (int)__popcll(same));
        base = __shfl(base, leader);
        if (valid && (row == lrow)) {
            int off = (int)__popcll(same & ((1ull << lane) - 1ull));
            int rank = base + off;
            if (rank < CAPR) bucket2[lrow * CAPR + rank] = make_int2(__float_as_int(dv), meta);
        }
        active &= ~same;
    }
}

// One block per (row=(b,nz), c-chunk of 4). LDS acc[4][64*64] (4x16KB planes):
// scan-phase atomics land on bank nxny%32 (random ~2-way); drain is contiguous
// ds_read_b128 -> fully coalesced contiguous 16KB plane stores.
__global__ __launch_bounds__(256) void lss_out4(
    const float* __restrict__ featT,
    const int* __restrict__ cnt, const int2* __restrict__ bucket2,
    float* __restrict__ out)
{
    int bid = blockIdx.x;
    int ccb = bid & 15;                    // which 4-channel chunk
    int row = bid >> 4;                    // b*GZ + nz
    int b = row >> 5;
    int nz = row & 31;
    int tid = threadIdx.x;

    int scnt = cnt[row];
    if (scnt > CAPR) scnt = CAPR;

    size_t ob0 = (((size_t)b * CC + ccb * 4) * GZZ + nz) * (GXX * GYY);
    const size_t cstride = (size_t)GZZ * GXX * GYY;   // channel plane stride

    if (scnt == 0) {
        float4 z = make_float4(0.f, 0.f, 0.f, 0.f);
        #pragma unroll
        for (int cc = 0; cc < 4; ++cc) {
            size_t ob = ob0 + (size_t)cc * cstride;
            for (int i = tid; i < 1024; i += 256)
                *(float4*)(out + ob + i * 4) = z;
        }
        return;
    }

    __shared__ float acc[4][GXX * GYY];    // 64 KB total, 4 contiguous planes
    {
        float4 z = make_float4(0.f, 0.f, 0.f, 0.f);
        float4* a4 = (float4*)acc;
        for (int i = tid; i < 4 * GXX * GYY / 4; i += 256) a4[i] = z;
    }
    __syncthreads();

    const float4* fT = (const float4*)featT;   // fT[site*16 + ccb]
    const int2* bk = bucket2 + (size_t)row * CAPR;
    for (int e = tid; e < scnt; e += 256) {
        int2 en = bk[e];
        float dv = __int_as_float(en.x);
        int meta = en.y;
        int site = meta >> 12;
        int nxny = meta & 4095;            // (nx<<6)|ny
        float4 f = fT[site * 16 + ccb];
        atomicAdd(&acc[0][nxny], dv * f.x);
        atomicAdd(&acc[1][nxny], dv * f.y);
        atomicAdd(&acc[2][nxny], dv * f.z);
        atomicAdd(&acc[3][nxny], dv * f.w);
    }
    __syncthreads();

    #pragma unroll
    for (int cc = 0; cc < 4; ++cc) {
        const float4* a4 = (const float4*)acc[cc];
        size_t ob = ob0 + (size_t)cc * cstride;
        for (int i = tid; i < 1024; i += 256)
            *(float4*)(out + ob + i * 4) = a4[i];   // conflict-free b128 read, coalesced store
    }
}

// ---- fallback (R1 path) ----
__global__ __launch_bounds__(256) void lss_scatter_direct(
    const float* __restrict__ depth, const float* __restrict__ feature,
    const float* __restrict__ rots, const float* __restrict__ trans,
    const float* __restrict__ intr, float* __restrict__ out)
{
    int p = blockIdx.x * 4 + (threadIdx.x >> 6);
    int lane = threadIdx.x & 63;
    int w = p % FWW;
    int t = p / FWW;
    int h = t % FHH; t /= FHH;
    int di = t % DD; t /= DD;
    int n = t % NN;
    int b = t / NN;
    float d = (float)(di + 1);
    float x = (float)(351.0 * (double)w / 21.0);
    float y = (float)(127.0 * (double)h / 7.0);
    const float* K = intr + (b * NN + n) * 9;
    double k00 = K[0], k01 = K[1], k02 = K[2];
    double k10 = K[3], k11 = K[4], k12 = K[5];
    double k20 = K[6], k21 = K[7], k22 = K[8];
    double det = k00*(k11*k22-k12*k21) - k01*(k10*k22-k12*k20) + k02*(k10*k21-k11*k20);
    double id = 1.0 / det;
    float i00=(float)((k11*k22-k12*k21)*id), i01=(float)((-k01*k22+k02*k21)*id), i02=(float)((k01*k12-k02*k11)*id);
    float i10=(float)((-k10*k22+k12*k20)*id), i11=(float)((k00*k22-k02*k20)*id), i12=(float)((-k00*k12+k02*k10)*id);
    float i20=(float)((k10*k21-k11*k20)*id), i21=(float)((-k00*k21+k01*k20)*id), i22=(float)((k00*k11-k01*k10)*id);
    float p0 = x * d, p1 = y * d, p2 = d;
    float c0 = i00*p0 + i01*p1 + i02*p2;
    float c1 = i10*p0 + i11*p1 + i12*p2;
    float c2 = i20*p0 + i21*p1 + i22*p2;
    const float* R = rots + (b * NN + n) * 9;
    const float* T = trans + (b * NN + n) * 3;
    float g0 = R[0]*c0 + R[1]*c1 + R[2]*c2 + T[0];
    float g1 = R[3]*c0 + R[4]*c1 + R[5]*c2 + T[1];
    float g2 = R[6]*c0 + R[7]*c1 + R[8]*c2 + T[2];
    int nx = (int)((g0 + 16.0f) / 0.5f);
    int ny = (int)((g2 + 16.0f) / 0.5f);
    int nz = (int)((g1 + 8.0f)  / 0.5f);
    if (!((nx >= 0) & (nx < GXX) & (ny >= 0) & (ny < GYY) & (nz >= 0) & (nz < GZZ)))
        return;
    float dv = depth[(((b * NN + n) * DD + di) * FHH + h) * FWW + w];
    float fv = feature[(((b * NN + n) * CC + lane) * FHH + h) * FWW + w];
    size_t oidx = ((((size_t)b * CC + lane) * GZZ + nz) * GXX + nx) * GYY + ny;
    atomicAdd(out + oidx, dv * fv);
}

extern "C" void kernel_launch(void* const* d_in, const int* in_sizes, int n_in,
                              void* d_out, int out_size, void* d_ws, size_t ws_size,
                              hipStream_t stream) {
    const float* depth   = (const float*)d_in[0];
    const float* feature = (const float*)d_in[1];
    const float* rots    = (const float*)d_in[2];
    const float* trans   = (const float*)d_in[3];
    const float* intr    = (const float*)d_in[4];
    float* out = (float*)d_out;

    if (ws_size >= WS_NEEDED) {
        int*   cnt     = (int*)((char*)d_ws + WS_CNT_OFF);
        int2*  bucket2 = (int2*)((char*)d_ws + WS_BUCKET_OFF);
        float* featT   = (float*)((char*)d_ws + WS_FEATT_OFF);

        // 1) featT transpose + zero row counts
        lss_featT<<<NFEATT / 256, 256, 0, stream>>>(feature, featT, cnt);
        // 2) build per-(b,nz)-row buckets (depth premultiplied into entries)
        lss_build<<<NPOINTS / 256, 256, 0, stream>>>(depth, rots, trans, intr, cnt, bucket2);
        // 3) dense output: conflict-free LDS drain + contiguous 16KB-plane writes
        lss_out4<<<ROWS * 16, 256, 0, stream>>>(featT, cnt, bucket2, out);
    } else {
        lss_zero<<<4096, 256, 0, stream>>>((float4*)out, out_size / 4);
        lss_scatter_direct<<<NPOINTS / 4, 256, 0, stream>>>(depth, feature, rots, trans, intr, out);
    }
}